// Round 2
// baseline (71.749 us; speedup 1.0000x reference)
//
#include <hip/hip_runtime.h>
#include <hip/hip_bf16.h>

// DenseQConv1D — algebraic collapse.
//
// out[c,n] = sum_e sign[e] * (sum_d s_d * (E@R_c)[d,e])^2, s = patch/||p||,
// patch dim 128 of 512, sign[e] = +-1 by MSB of e.
//
// E is a permutation (ring of CNOTs): (E@R)[d,e] = R[g(d), e], and
// sum_e sign[e] R[a,e] R[b,e] = (R Z R^T)[a,b] = (G (x) I_256)[a,b]
//   (qubits 1..8: RY RY^T = I; qubit 0: G = [[cos t, sin t],[sin t, -cos t]],
//    t = theta[c,0] — theta[:,1:] provably cancels).
// => out[c,n] = (cos t_c * A_n + sin t_c * B_n) / ||p||^2
//    A_n = sum_{d<128} sgn(g(d)>>8) p_d^2
//    B_n = sum_{d<128, partner} p_d * p_{ginv[g(d)^256]}  (partner must be <128)
//
// g is analytic: g = f0∘f1∘…∘f8, f_q(i) = (i & 1<<(8-q)) ? i ^ (1<<(8-(q+1)%9)) : i.
//
// Dtype self-detection: E[0][0] == 1.0 exactly (g(0)=0). First uint16 word of
// the E buffer is 0x3F80 iff bf16, 0x0000 iff fp32 (LE low half of 1.0f).

#define NQ    9
#define DIM   512
#define CIN   16
#define KS    8
#define COUT  16
#define NB    8
#define LIN   1024
#define LOUT  (LIN - KS + 1)   // 1017
#define TILE  256
#define SPAN  (TILE + KS - 1)  // 263

__global__ __launch_bounds__(256) void qconv_kernel(
    const void* __restrict__ xp,
    const void* __restrict__ thetap,
    const void* __restrict__ Ep,
    void* __restrict__ outp)
{
    __shared__ int   gperm[DIM];
    __shared__ int   ginv[DIM];
    __shared__ float gsign[128];
    __shared__ int   gpart[128];
    __shared__ float csn[2][COUT];
    __shared__ float xs[CIN][SPAN];
    __shared__ int   isbf_s;

    const int tid  = threadIdx.x;
    const int b    = blockIdx.x >> 2;   // 4 tiles per batch
    const int tile = blockIdx.x & 3;
    const int l0   = tile * TILE;

    // --- dtype probe: one uint16 load from E ---
    if (tid == 0) {
        isbf_s = (((const unsigned short*)Ep)[0] == 0x3F80) ? 1 : 0;
    }

    // --- analytic permutation g(d) = f0(f1(...f8(d))) ---
    for (int d = tid; d < DIM; d += 256) {
        int v = d;
        #pragma unroll
        for (int q = NQ - 1; q >= 0; --q) {
            int bc = 1 << (NQ - 1 - q);
            int bt = 1 << (NQ - 1 - ((q + 1) % NQ));
            if (v & bc) v ^= bt;
        }
        gperm[d] = v;
    }
    __syncthreads();

    const int isbf = isbf_s;
    const __hip_bfloat16* xb = (const __hip_bfloat16*)xp;
    const float*          xf = (const float*)xp;

    for (int d = tid; d < DIM; d += 256) ginv[gperm[d]] = d;

    // cos/sin of theta[c,0]
    if (tid < COUT) {
        float t = isbf ? __bfloat162float(((const __hip_bfloat16*)thetap)[tid * NQ])
                       : ((const float*)thetap)[tid * NQ];
        csn[0][tid] = cosf(t);
        csn[1][tid] = sinf(t);
    }
    __syncthreads();

    if (tid < 128) {
        int g = gperm[tid];
        gsign[tid] = (g & 256) ? -1.0f : 1.0f;
        int p = ginv[g ^ 256];
        gpart[tid] = (p < 128 && p != tid) ? p : -1;
    }

    // --- stage x tile into LDS as fp32 ---
    for (int idx = tid; idx < CIN * SPAN; idx += 256) {
        int ci = idx / SPAN;
        int j  = idx - ci * SPAN;
        int l  = l0 + j;
        float v = 0.0f;
        if (l < LIN) {
            int gi = (b * CIN + ci) * LIN + l;
            v = isbf ? __bfloat162float(xb[gi]) : xf[gi];
        }
        xs[ci][j] = v;
    }
    __syncthreads();

    // --- one thread per output position l ---
    const int l = l0 + tid;
    if (l < LOUT) {
        float n2 = 0.f, A = 0.f, Bv = 0.f;
        for (int d = 0; d < 128; ++d) {
            const int ci = d >> 3, t = d & 7;
            float pd = xs[ci][tid + t];
            n2 += pd * pd;
            A  += gsign[d] * (pd * pd);
            int pt = gpart[d];
            if (pt >= 0) {
                float pp = xs[pt >> 3][tid + (pt & 7)];
                Bv += pd * pp;
            }
        }
        const float inv = 1.0f / fmaxf(n2, 1e-24f);
        A *= inv; Bv *= inv;
        #pragma unroll
        for (int c = 0; c < COUT; ++c) {
            float val = csn[0][c] * A + csn[1][c] * Bv;
            int oi = (b * COUT + c) * LOUT + l;
            if (isbf) ((__hip_bfloat16*)outp)[oi] = __float2bfloat16(val);
            else      ((float*)outp)[oi] = val;
        }
    }
}

extern "C" void kernel_launch(void* const* d_in, const int* in_sizes, int n_in,
                              void* d_out, int out_size, void* d_ws, size_t ws_size,
                              hipStream_t stream) {
    (void)in_sizes; (void)n_in; (void)out_size; (void)d_ws; (void)ws_size;
    qconv_kernel<<<dim3(NB * 4), dim3(256), 0, stream>>>(d_in[0], d_in[1], d_in[2], d_out);
}

// Round 3
// 67.499 us; speedup vs baseline: 1.0630x; 1.0630x over previous
//
#include <hip/hip_runtime.h>
#include <hip/hip_bf16.h>

// DenseQConv1D — algebraic collapse (see R2 derivation, bench-verified):
//   out[c,n] = (cos t_c * A_n + sin t_c * B_n) / ||p||^2,  t_c = theta[c,0]
//   A_n = sum_{d<128} sgn(g(d)&256) p_d^2
//   B_n = 2 * sum_{d<p(d)} p_d * p_{p(d)},  p(d) = ginv[g(d)^256] if <128
// g analytic (ring of CNOTs) => sign/partner tables are COMPILE-TIME constants.
// theta[:,1:] provably cancels; E only used as a dtype probe (E[0][0]==1.0:
// first uint16 word 0x3F80 iff bf16, 0x0000 iff fp32).

#define NQ    9
#define DIM   512
#define CIN   16
#define KS    8
#define COUT  16
#define NB    8
#define LIN   1024
#define LOUT  (LIN - KS + 1)      // 1017
#define TILE  64
#define BLOCK 64
#define SPAN  (TILE + KS - 1)     // 71
#define NTILE ((LOUT + TILE - 1) / TILE)  // 16

struct Tab { int part[128]; int signpos[128]; };
constexpr Tab make_tab() {
    Tab t{};
    int g[DIM] = {}, inv[DIM] = {};
    for (int i = 0; i < DIM; ++i) {
        int v = i;
        for (int q = NQ - 1; q >= 0; --q) {
            int bc = 1 << (NQ - 1 - q);
            int bt = 1 << (NQ - 1 - ((q + 1) % NQ));
            if (v & bc) v ^= bt;
        }
        g[i] = v;
    }
    for (int i = 0; i < DIM; ++i) inv[g[i]] = i;
    for (int d = 0; d < 128; ++d) {
        t.signpos[d] = (g[d] & 256) ? 0 : 1;
        int p = inv[g[d] ^ 256];
        t.part[d] = (p < 128) ? p : -1;
    }
    return t;
}
constexpr Tab TAB = make_tab();

__global__ __launch_bounds__(BLOCK) void qconv_kernel(
    const void* __restrict__ xp,
    const void* __restrict__ thetap,
    const void* __restrict__ Ep,
    void* __restrict__ outp)
{
    __shared__ float xs[CIN][SPAN];
    __shared__ float csn[2][COUT];

    const int tid  = threadIdx.x;
    const int b    = blockIdx.x >> 4;     // NTILE = 16
    const int tile = blockIdx.x & 15;
    const int l0   = tile * TILE;

    const int isbf = (((const unsigned short*)Ep)[0] == 0x3F80) ? 1 : 0;
    const __hip_bfloat16* xb = (const __hip_bfloat16*)xp;
    const float*          xf = (const float*)xp;

    // cos/sin of theta[c,0]
    if (tid < COUT) {
        float t = isbf ? __bfloat162float(((const __hip_bfloat16*)thetap)[tid * NQ])
                       : ((const float*)thetap)[tid * NQ];
        csn[0][tid] = cosf(t);
        csn[1][tid] = sinf(t);
    }

    // stage x tile (fp32 in LDS). l0+tid <= 960+63 = 1023: no guard on the
    // main element; halo (tid < SPAN-TILE = 7) needs a bound check.
    #pragma unroll
    for (int ci = 0; ci < CIN; ++ci) {
        const int gi = (b * CIN + ci) * LIN + l0 + tid;
        xs[ci][tid] = isbf ? __bfloat162float(xb[gi]) : xf[gi];
        if (tid < SPAN - TILE) {
            const int l = l0 + TILE + tid;
            float v = 0.0f;
            if (l < LIN) v = isbf ? __bfloat162float(xb[gi + TILE]) : xf[gi + TILE];
            xs[ci][TILE + tid] = v;
        }
    }
    __syncthreads();

    const int l = l0 + tid;
    if (l < LOUT) {
        // preload the 128-element window into registers
        float w[CIN][KS];
        #pragma unroll
        for (int ci = 0; ci < CIN; ++ci)
            #pragma unroll
            for (int t = 0; t < KS; ++t)
                w[ci][t] = xs[ci][tid + t];

        float sp = 0.f, sm = 0.f, bv = 0.f;
        #pragma unroll
        for (int d = 0; d < 128; ++d) {
            const float pd = w[d >> 3][d & 7];
            if (TAB.signpos[d]) sp += pd * pd; else sm += pd * pd;
            const int p = TAB.part[d];
            if (p > d) bv += pd * w[p >> 3][p & 7];   // constant-folded guard
        }
        const float n2  = sp + sm;
        const float inv = 1.0f / fmaxf(n2, 1e-24f);
        const float A   = (sp - sm) * inv;
        const float Bv  = 2.0f * bv * inv;

        #pragma unroll
        for (int c = 0; c < COUT; ++c) {
            const float val = csn[0][c] * A + csn[1][c] * Bv;
            const int oi = (b * COUT + c) * LOUT + l;
            if (isbf) ((__hip_bfloat16*)outp)[oi] = __float2bfloat16(val);
            else      ((float*)outp)[oi] = val;
        }
    }
}

extern "C" void kernel_launch(void* const* d_in, const int* in_sizes, int n_in,
                              void* d_out, int out_size, void* d_ws, size_t ws_size,
                              hipStream_t stream) {
    (void)in_sizes; (void)n_in; (void)out_size; (void)d_ws; (void)ws_size;
    qconv_kernel<<<dim3(NB * NTILE), dim3(BLOCK), 0, stream>>>(d_in[0], d_in[1], d_in[2], d_out);
}

// Round 4
// 63.509 us; speedup vs baseline: 1.1297x; 1.0628x over previous
//
#include <hip/hip_runtime.h>
#include <hip/hip_bf16.h>

// DenseQConv1D — algebraic collapse (bench-verified R2/R3):
//   out[c,n] = (cos t_c * A_n + sin t_c * B_n) / ||p||^2,  t_c = theta[c,0]
//   A_n = sum_{d<128} sgn(g(d)&256) p_d^2
//   B_n = 2 * sum_{d<p(d)} p_d * p_{p(d)},  p(d) = ginv[g(d)^256] if <128
// g analytic (ring of CNOTs) => sign/partner tables are COMPILE-TIME constants.
// theta[:,1:] provably cancels; E only used as a dtype probe (E[0][0]==1.0:
// first uint16 word 0x3F80 iff bf16 layout, 0x0000 iff fp32 (LE)).
// R1/R2/R3 evidence: data is fp32; bf16 path kept as a zero-cost fallback.

#define NQ    9
#define DIM   512
#define CIN   16
#define KS    8
#define COUT  16
#define NB    8
#define LIN   1024
#define LOUT  (LIN - KS + 1)      // 1017
#define TILE  64
#define BLOCK 64
#define SPAN  (TILE + KS - 1)     // 71
#define XSW   72                  // LDS row width (float4-writable, 71 used)
#define NTILE ((LOUT + TILE - 1) / TILE)  // 16

struct Tab { int part[128]; int signpos[128]; };
constexpr Tab make_tab() {
    Tab t{};
    int g[DIM] = {}, inv[DIM] = {};
    for (int i = 0; i < DIM; ++i) {
        int v = i;
        for (int q = NQ - 1; q >= 0; --q) {
            int bc = 1 << (NQ - 1 - q);
            int bt = 1 << (NQ - 1 - ((q + 1) % NQ));
            if (v & bc) v ^= bt;
        }
        g[i] = v;
    }
    for (int i = 0; i < DIM; ++i) inv[g[i]] = i;
    for (int d = 0; d < 128; ++d) {
        t.signpos[d] = (g[d] & 256) ? 0 : 1;
        int p = inv[g[d] ^ 256];
        t.part[d] = (p < 128) ? p : -1;
    }
    return t;
}
constexpr Tab TAB = make_tab();

__global__ __launch_bounds__(BLOCK) void qconv_kernel(
    const void* __restrict__ xp,
    const void* __restrict__ thetap,
    const void* __restrict__ Ep,
    void* __restrict__ outp)
{
    __shared__ float xs[CIN][XSW];
    __shared__ float csn[2][COUT];

    const int tid = threadIdx.x;
    const int b   = blockIdx.x >> 4;     // NTILE = 16
    const int l0  = (blockIdx.x & 15) * TILE;

    const int isbf = (((const unsigned short*)Ep)[0] == 0x3F80) ? 1 : 0;

    // cos/sin of theta[c,0]
    if (tid < COUT) {
        float t = isbf ? __bfloat162float(((const __hip_bfloat16*)thetap)[tid * NQ])
                       : ((const float*)thetap)[tid * NQ];
        csn[0][tid] = cosf(t);
        csn[1][tid] = sinf(t);
    }

    // --- stage x tile into LDS (fp32), wave-uniform dtype branch ---
    if (!isbf) {
        const float* xf = (const float*)xp;
        // 16 rows x 18 float4 jobs = 288
        for (int job = tid; job < CIN * 18; job += BLOCK) {
            const int ci = job / 18;
            const int v  = job - ci * 18;
            const int c0 = 4 * v;
            const float* src = xf + (b * CIN + ci) * LIN + l0 + c0;
            if (c0 + 3 < SPAN && l0 + c0 + 3 < LIN) {      // fast: aligned float4
                *(float4*)&xs[ci][c0] = *(const float4*)src;
            } else {                                        // tail / halo guard
                #pragma unroll
                for (int e = 0; e < 4; ++e) {
                    const int l = l0 + c0 + e;
                    xs[ci][c0 + e] = (l < LIN) ? src[e] : 0.0f;
                }
            }
        }
    } else {
        const __hip_bfloat16* xb = (const __hip_bfloat16*)xp;
        for (int idx = tid; idx < CIN * XSW; idx += BLOCK) {
            const int ci = idx / XSW;
            const int j  = idx - ci * XSW;
            const int l  = l0 + j;
            float v = 0.0f;
            if (l < LIN && j < SPAN)
                v = __bfloat162float(xb[(b * CIN + ci) * LIN + l]);
            xs[ci][j] = v;
        }
    }
    __syncthreads();

    const int l = l0 + tid;
    if (l < LOUT) {
        // preload the 128-element window into registers
        float w[CIN][KS];
        #pragma unroll
        for (int ci = 0; ci < CIN; ++ci)
            #pragma unroll
            for (int t = 0; t < KS; ++t)
                w[ci][t] = xs[ci][tid + t];

        float sp = 0.f, sm = 0.f, bv = 0.f;
        #pragma unroll
        for (int d = 0; d < 128; ++d) {
            const float pd = w[d >> 3][d & 7];
            if (TAB.signpos[d]) sp += pd * pd; else sm += pd * pd;
            const int p = TAB.part[d];
            if (p > d) bv += pd * w[p >> 3][p & 7];   // constant-folded guard
        }
        const float n2  = sp + sm;
        const float inv = 1.0f / fmaxf(n2, 1e-24f);
        const float A   = (sp - sm) * inv;
        const float Bv  = 2.0f * bv * inv;

        #pragma unroll
        for (int c = 0; c < COUT; ++c) {
            const float val = csn[0][c] * A + csn[1][c] * Bv;
            const int oi = (b * COUT + c) * LOUT + l;
            if (isbf) ((__hip_bfloat16*)outp)[oi] = __float2bfloat16(val);
            else      ((float*)outp)[oi] = val;
        }
    }
}

extern "C" void kernel_launch(void* const* d_in, const int* in_sizes, int n_in,
                              void* d_out, int out_size, void* d_ws, size_t ws_size,
                              hipStream_t stream) {
    (void)in_sizes; (void)n_in; (void)out_size; (void)d_ws; (void)ws_size;
    qconv_kernel<<<dim3(NB * NTILE), dim3(BLOCK), 0, stream>>>(d_in[0], d_in[1], d_in[2], d_out);
}